// Round 9
// baseline (179.675 us; speedup 1.0000x reference)
//
#include <hip/hip_runtime.h>
#include <math.h>

#define N_ 16
#define C_ 4
#define F_ 257
#define T_ 1000
#define B_ 8
#define K_ 80
#define BK_ 640
#define TT_ 16
#define NT_ 63            // ceil(1000/16)
#define NBLK (N_ * NT_)   // 1008 blocks ~= 4 per CU
#define MSTR 262          // magS row stride (words): 2-way max on b64 reads
#define WKS  80           // wT row stride: plain [f][k]

// d_ws byte offsets
#define WT_OFF   0                            // 257*80*4 = 82240 B
#define PART_OFF (128 * 1024)
#define SS_OFF   (PART_OFF + NBLK * 16 * 8)

// ---- transpose w_proj [k][f] -> wT[f][k] ----
__global__ __launch_bounds__(80) void k_wt(const float* __restrict__ wp,
                                           float* __restrict__ wT) {
    int f = blockIdx.x;
    int k = threadIdx.x;
    wT[f * WKS + k] = wp[k * F_ + f];
}

// Fused beamform+mag (LDS) + projection GEMM (w scalar/SGPR) + relu+log
// + BN partial sums.  Block = (n, 16-t tile), all 8 b, all 80 k.
// GEMM roles: wave kg=tid>>6 owns 20 k's (wave-uniform -> s_load);
//   lane: t_loc=tid&15, bq=(tid>>4)&3 (2 b's) -> 2b x 20k x 1t = 40 acc.
// Staging roles: sfr=tid>>3 (f-row 0..31), st2=tid&7 (2 t's each), all 8 b.
__global__ __launch_bounds__(256, 4) void k_fused(
    const float* __restrict__ xr, const float* __restrict__ xi,
    const float* __restrict__ wr, const float* __restrict__ wi,
    const float* __restrict__ wT,
    float* __restrict__ out, double* __restrict__ partials) {

    const int tid = threadIdx.x;
    const int bid = blockIdx.x;
    const int tt = bid % NT_;
    const int n  = bid / NT_;
    const int t0 = tt * TT_;

    __shared__ float magS[TT_][MSTR];   // [t][f*8 + b]  16.8 KB
    __shared__ double redS1[4][4][2];
    __shared__ double redS2[4][4][2];

    const int t_loc = tid & 15;
    const int bq    = (tid >> 4) & 3;                            // 2 b's: bq*2
    const int kg    = __builtin_amdgcn_readfirstlane(tid >> 6);  // 20 k's

    const int sfr = tid >> 3;           // staging f-row 0..31
    const int st2 = tid & 7;            // staging t-pair
    const int tb  = t0 + st2 * 2;
    const bool tload = (tb + 2 <= T_);

    float acc[2][20];
#pragma unroll
    for (int i = 0; i < 2; ++i)
#pragma unroll
        for (int j = 0; j < 20; ++j) acc[i][j] = 0.f;

    const float* xrn = xr + (size_t)n * C_ * F_ * T_;
    const float* xin = xi + (size_t)n * C_ * F_ * T_;

    // -------- prefetch x for chunk 0 --------
    float2 pxr[C_], pxi[C_];
    if (tload) {
        const float* xrp = xrn + (size_t)sfr * T_ + tb;
        const float* xip = xin + (size_t)sfr * T_ + tb;
#pragma unroll
        for (int c = 0; c < C_; ++c) {
            pxr[c] = *(const float2*)(xrp + (size_t)c * F_ * T_);
            pxi[c] = *(const float2*)(xip + (size_t)c * F_ * T_);
        }
    }

    for (int ch = 0; ch < 8; ++ch) {
        const int f0 = ch * 32;
        const int f  = f0 + sfr;

        __syncthreads();   // previous GEMM done reading magS

        // ---- beamform mag into LDS: thread = (f-row sfr, t-pair st2) ----
        {
            float m[2][B_];
            if (tload) {
                float xrv[C_][2], xiv[C_][2];
#pragma unroll
                for (int c = 0; c < C_; ++c) {
                    xrv[c][0] = pxr[c].x; xrv[c][1] = pxr[c].y;
                    xiv[c][0] = pxi[c].x; xiv[c][1] = pxi[c].y;
                }
                const float* wrp = wr + (size_t)f * B_ * C_;
                const float* wip = wi + (size_t)f * B_ * C_;
#pragma unroll
                for (int b = 0; b < B_; ++b) {
                    float4 wrv = *(const float4*)(wrp + b * C_);
                    float4 wiv = *(const float4*)(wip + b * C_);
                    float wrc[4] = {wrv.x, wrv.y, wrv.z, wrv.w};
                    float wic[4] = {wiv.x, wiv.y, wiv.z, wiv.w};
#pragma unroll
                    for (int i = 0; i < 2; ++i) {
                        float br = 0.f, bi2 = 0.f;
#pragma unroll
                        for (int c = 0; c < C_; ++c) {
                            br  += xrv[c][i] * wrc[c] - xiv[c][i] * wic[c];
                            bi2 += xiv[c][i] * wrc[c] + xrv[c][i] * wic[c];
                        }
                        m[i][b] = sqrtf(br * br + bi2 * bi2 + 1e-5f);
                    }
                }
            } else {
#pragma unroll
                for (int i = 0; i < 2; ++i)
#pragma unroll
                    for (int b = 0; b < B_; ++b) m[i][b] = 0.f;
            }
#pragma unroll
            for (int i = 0; i < 2; ++i) {
                *(float4*)&magS[st2 * 2 + i][sfr * 8] =
                    make_float4(m[i][0], m[i][1], m[i][2], m[i][3]);
                *(float4*)&magS[st2 * 2 + i][sfr * 8 + 4] =
                    make_float4(m[i][4], m[i][5], m[i][6], m[i][7]);
            }
        }

        // ---- issue x prefetch for ch+1 ----
        if (ch < 7 && tload) {
            const float* xrp = xrn + (size_t)(f0 + 32 + sfr) * T_ + tb;
            const float* xip = xin + (size_t)(f0 + 32 + sfr) * T_ + tb;
#pragma unroll
            for (int c = 0; c < C_; ++c) {
                pxr[c] = *(const float2*)(xrp + (size_t)c * F_ * T_);
                pxi[c] = *(const float2*)(xip + (size_t)c * F_ * T_);
            }
        }

        __syncthreads();

        // ---- GEMM over 32 f rows: mag 1xb64 LDS, w scalar (SGPR) ----
        const float* wchunk = wT + (size_t)f0 * WKS + kg * 20;  // wave-uniform
#pragma unroll 4
        for (int fc = 0; fc < 32; ++fc) {
            float2 mv = *(const float2*)&magS[t_loc][fc * 8 + bq * 2];
            float wv[20];
#pragma unroll
            for (int j = 0; j < 20; ++j) wv[j] = wchunk[fc * WKS + j];
#pragma unroll
            for (int j = 0; j < 20; ++j) {
                acc[0][j] += mv.x * wv[j];
                acc[1][j] += mv.y * wv[j];
            }
        }
    }

    // ---- tail f = 256 ----
    __syncthreads();
    if (tid < 128) {
        int trow = tid >> 3;
        int b = tid & 7;
        int t = t0 + trow;
        float v = 0.f;
        if (t < T_) {
            const float* wrp = wr + (size_t)(256 * B_ + b) * C_;
            const float* wip = wi + (size_t)(256 * B_ + b) * C_;
            float br = 0.f, bi2 = 0.f;
#pragma unroll
            for (int c = 0; c < C_; ++c) {
                float xrv = xrn[((size_t)c * F_ + 256) * T_ + t];
                float xiv = xin[((size_t)c * F_ + 256) * T_ + t];
                br  += xrv * wrp[c] - xiv * wip[c];
                bi2 += xiv * wrp[c] + xrv * wip[c];
            }
            v = sqrtf(br * br + bi2 * bi2 + 1e-5f);
        }
        magS[trow][b] = v;
    }
    __syncthreads();
    {
        float2 mv = *(const float2*)&magS[t_loc][bq * 2];
        const float* wtail = wT + (size_t)256 * WKS + kg * 20;
#pragma unroll
        for (int j = 0; j < 20; ++j) {
            float wv = wtail[j];
            acc[0][j] += mv.x * wv;
            acc[1][j] += mv.y * wv;
        }
    }

    // ---- epilogue: relu+log, store (float4), per-b BN partial sums ----
    float s1f[2], s2f[2];
    s1f[0] = s1f[1] = s2f[0] = s2f[1] = 0.f;
    const int t = t0 + t_loc;
    if (t < T_) {
        float* obase = out + ((size_t)n * T_ + t) * BK_ + (bq * 2) * K_ + kg * 20;
#pragma unroll
        for (int i = 0; i < 2; ++i) {
            float vv[20];
#pragma unroll
            for (int j = 0; j < 20; ++j) {
                float v = fmaxf(acc[i][j], 0.0f);
                v = __logf(v + 1e-5f);
                vv[j] = v;
                s1f[i] += v;
                s2f[i] += v * v;
            }
            float* orow = obase + i * K_;
#pragma unroll
            for (int q = 0; q < 5; ++q)
                *(float4*)(orow + q * 4) =
                    make_float4(vv[q * 4], vv[q * 4 + 1], vv[q * 4 + 2], vv[q * 4 + 3]);
        }
    }
    const int wav = tid >> 6;
#pragma unroll
    for (int i = 0; i < 2; ++i) {
        double d1 = (double)s1f[i], d2 = (double)s2f[i];
#pragma unroll
        for (int off = 1; off < 16; off <<= 1) {   // reduce over 16 t-lanes
            d1 += __shfl_xor(d1, off);
            d2 += __shfl_xor(d2, off);
        }
        if (t_loc == 0) { redS1[wav][bq][i] = d1; redS2[wav][bq][i] = d2; }
    }
    __syncthreads();
    if (tid < 8) {   // b = tid = 2*(tid>>1) + (tid&1)
        int bqi = tid >> 1, ii = tid & 1;
        partials[(size_t)bid * 16 + tid] =
            redS1[0][bqi][ii] + redS1[1][bqi][ii] + redS1[2][bqi][ii] + redS1[3][bqi][ii];
    } else if (tid >= 64 && tid < 72) {
        int id = tid - 64;
        int bqi = id >> 1, ii = id & 1;
        partials[(size_t)bid * 16 + 8 + id] =
            redS2[0][bqi][ii] + redS2[1][bqi][ii] + redS2[2][bqi][ii] + redS2[3][bqi][ii];
    }
}

// ---------------- reduce partials -> per-channel scale/shift ----------------
__global__ __launch_bounds__(256) void k_bnstats(
    const double* __restrict__ partials,
    const float* __restrict__ gamma, const float* __restrict__ beta,
    float* __restrict__ ss) {
    const int b = threadIdx.x >> 5;
    const int i = threadIdx.x & 31;
    double s1 = 0.0, s2 = 0.0;
    for (int j = i; j < NBLK; j += 32) {
        s1 += partials[(size_t)j * 16 + b];
        s2 += partials[(size_t)j * 16 + 8 + b];
    }
#pragma unroll
    for (int off = 16; off; off >>= 1) {
        s1 += __shfl_down(s1, off);
        s2 += __shfl_down(s2, off);
    }
    if (i == 0) {
        const double cnt = (double)N_ * T_ * K_;
        double mean = s1 / cnt;
        double var = s2 / cnt - mean * mean;
        float scale = gamma[b] * (float)(1.0 / sqrt(var + 1e-5));
        float shift = beta[b] - (float)mean * scale;
        ss[b] = scale;
        ss[B_ + b] = shift;
    }
}

// ---------------- apply BN in place over d_out ----------------
__global__ __launch_bounds__(256) void k_bnapply(float* __restrict__ out,
                                                 const float* __restrict__ ss) {
    size_t i4 = (size_t)blockIdx.x * 256 + threadIdx.x;
    int k4 = (int)(i4 % (BK_ / 4));
    int b = k4 / (K_ / 4);
    float scale = ss[b], shift = ss[B_ + b];
    float4* p = (float4*)out + i4;
    float4 v = *p;
    v.x = v.x * scale + shift;
    v.y = v.y * scale + shift;
    v.z = v.z * scale + shift;
    v.w = v.w * scale + shift;
    *p = v;
}

extern "C" void kernel_launch(void* const* d_in, const int* in_sizes, int n_in,
                              void* d_out, int out_size, void* d_ws, size_t ws_size,
                              hipStream_t stream) {
    const float* xr = (const float*)d_in[0];
    const float* xi = (const float*)d_in[1];
    const float* wr = (const float*)d_in[2];
    const float* wi = (const float*)d_in[3];
    const float* w_proj = (const float*)d_in[4];
    const float* gamma = (const float*)d_in[5];
    const float* beta = (const float*)d_in[6];
    float* out = (float*)d_out;

    float* wT = (float*)((char*)d_ws + WT_OFF);
    double* partials = (double*)((char*)d_ws + PART_OFF);
    float* ss = (float*)((char*)d_ws + SS_OFF);

    k_wt<<<F_, 80, 0, stream>>>(w_proj, wT);
    k_fused<<<NBLK, 256, 0, stream>>>(xr, xi, wr, wi, wT, out, partials);
    k_bnstats<<<1, 256, 0, stream>>>(partials, gamma, beta, ss);
    k_bnapply<<<10000, 256, 0, stream>>>(out, ss);
}

// Round 10
// 159.830 us; speedup vs baseline: 1.1242x; 1.1242x over previous
//
#include <hip/hip_runtime.h>
#include <math.h>

#define N_ 16
#define C_ 4
#define F_ 257
#define T_ 1000
#define B_ 8
#define K_ 80
#define BK_ 640
#define TT_ 16
#define NT_ 63            // ceil(1000/16)
#define NBLK (N_ * NT_)   // 1008 blocks ~= 4 per CU
#define MSTR 262          // magS row stride (words)
#define WKS  80           // wT row stride: plain [f][k]

// d_ws byte offsets
#define WT_OFF   0                            // 257*80*4 = 82240 B
#define PART_OFF (128 * 1024)
#define SS_OFF   (PART_OFF + NBLK * 16 * 8)

// ---- transpose w_proj [k][f] -> wT[f][k] ----
__global__ __launch_bounds__(80) void k_wt(const float* __restrict__ wp,
                                           float* __restrict__ wT) {
    int f = blockIdx.x;
    int k = threadIdx.x;
    wT[f * WKS + k] = wp[k * F_ + f];
}

// Fused beamform+mag (double-buffered LDS, 1 barrier/chunk) + projection GEMM
// (w scalar/SGPR) + relu+log + BN partial sums.
// Block = (n, 16-t tile), all 8 b, all 80 k.
// GEMM roles: wave kg=tid>>6 owns 20 k's (wave-uniform -> s_load);
//   lane: t_loc=tid&15, bq=(tid>>4)&3 (2 b's) -> 2b x 20k x 1t = 40 acc.
// Staging roles: sfr=tid>>3 (f-row 0..31), st2=tid&7 (2 t's each), all 8 b.
__global__ __launch_bounds__(256, 2) void k_fused(
    const float* __restrict__ xr, const float* __restrict__ xi,
    const float* __restrict__ wr, const float* __restrict__ wi,
    const float* __restrict__ wT,
    float* __restrict__ out, double* __restrict__ partials) {

    const int tid = threadIdx.x;
    const int bid = blockIdx.x;
    const int tt = bid % NT_;
    const int n  = bid / NT_;
    const int t0 = tt * TT_;

    __shared__ float magS[2][TT_][MSTR];   // double-buffered, 33.5 KB
    __shared__ double redS1[4][4][2];
    __shared__ double redS2[4][4][2];

    const int t_loc = tid & 15;
    const int bq    = (tid >> 4) & 3;                            // 2 b's: bq*2
    const int kg    = __builtin_amdgcn_readfirstlane(tid >> 6);  // 20 k's

    const int sfr = tid >> 3;           // staging f-row 0..31
    const int st2 = tid & 7;            // staging t-pair
    const int tb  = t0 + st2 * 2;
    const bool tload = (tb + 2 <= T_);

    float acc[2][20];
#pragma unroll
    for (int i = 0; i < 2; ++i)
#pragma unroll
        for (int j = 0; j < 20; ++j) acc[i][j] = 0.f;

    const float* xrn = xr + (size_t)n * C_ * F_ * T_;
    const float* xin = xi + (size_t)n * C_ * F_ * T_;

    // -------- prefetch x for chunk 0 --------
    float2 pxr[C_], pxi[C_];
    if (tload) {
        const float* xrp = xrn + (size_t)sfr * T_ + tb;
        const float* xip = xin + (size_t)sfr * T_ + tb;
#pragma unroll
        for (int c = 0; c < C_; ++c) {
            pxr[c] = *(const float2*)(xrp + (size_t)c * F_ * T_);
            pxi[c] = *(const float2*)(xip + (size_t)c * F_ * T_);
        }
    }

    for (int ch = 0; ch < 8; ++ch) {
        const int f0 = ch * 32;
        const int f  = f0 + sfr;
        const int pb = ch & 1;          // buffer being written this chunk

        // ---- beamform mag into LDS buf pb: thread = (sfr, st2) ----
        {
            float m[2][B_];
            if (tload) {
                float xrv[C_][2], xiv[C_][2];
#pragma unroll
                for (int c = 0; c < C_; ++c) {
                    xrv[c][0] = pxr[c].x; xrv[c][1] = pxr[c].y;
                    xiv[c][0] = pxi[c].x; xiv[c][1] = pxi[c].y;
                }
                const float* wrp = wr + (size_t)f * B_ * C_;
                const float* wip = wi + (size_t)f * B_ * C_;
#pragma unroll
                for (int b = 0; b < B_; ++b) {
                    float4 wrv = *(const float4*)(wrp + b * C_);
                    float4 wiv = *(const float4*)(wip + b * C_);
                    float wrc[4] = {wrv.x, wrv.y, wrv.z, wrv.w};
                    float wic[4] = {wiv.x, wiv.y, wiv.z, wiv.w};
#pragma unroll
                    for (int i = 0; i < 2; ++i) {
                        float br = 0.f, bi2 = 0.f;
#pragma unroll
                        for (int c = 0; c < C_; ++c) {
                            br  += xrv[c][i] * wrc[c] - xiv[c][i] * wic[c];
                            bi2 += xiv[c][i] * wrc[c] + xrv[c][i] * wic[c];
                        }
                        m[i][b] = sqrtf(br * br + bi2 * bi2 + 1e-5f);
                    }
                }
            } else {
#pragma unroll
                for (int i = 0; i < 2; ++i)
#pragma unroll
                    for (int b = 0; b < B_; ++b) m[i][b] = 0.f;
            }
#pragma unroll
            for (int i = 0; i < 2; ++i) {
                *(float4*)&magS[pb][st2 * 2 + i][sfr * 8] =
                    make_float4(m[i][0], m[i][1], m[i][2], m[i][3]);
                *(float4*)&magS[pb][st2 * 2 + i][sfr * 8 + 4] =
                    make_float4(m[i][4], m[i][5], m[i][6], m[i][7]);
            }
        }

        // ---- issue x prefetch for ch+1 (in flight across barrier+GEMM) ----
        if (ch < 7 && tload) {
            const float* xrp = xrn + (size_t)(f0 + 32 + sfr) * T_ + tb;
            const float* xip = xin + (size_t)(f0 + 32 + sfr) * T_ + tb;
#pragma unroll
            for (int c = 0; c < C_; ++c) {
                pxr[c] = *(const float2*)(xrp + (size_t)c * F_ * T_);
                pxi[c] = *(const float2*)(xip + (size_t)c * F_ * T_);
            }
        }

        __syncthreads();   // buf pb staged; prev GEMM (buf pb^1) already done

        // ---- GEMM over 32 f rows: mag 1xb64 LDS, w scalar (SGPR) ----
        const float* wchunk = wT + (size_t)f0 * WKS + kg * 20;  // wave-uniform
#pragma unroll 4
        for (int fc = 0; fc < 32; ++fc) {
            float2 mv = *(const float2*)&magS[pb][t_loc][fc * 8 + bq * 2];
            float wv[20];
#pragma unroll
            for (int j = 0; j < 20; ++j) wv[j] = wchunk[fc * WKS + j];
#pragma unroll
            for (int j = 0; j < 20; ++j) {
                acc[0][j] += mv.x * wv[j];
                acc[1][j] += mv.y * wv[j];
            }
        }
    }

    // ---- tail f = 256 (writes buf 0; GEMM(7) used buf 1) ----
    if (tid < 128) {
        int trow = tid >> 3;
        int b = tid & 7;
        int t = t0 + trow;
        float v = 0.f;
        if (t < T_) {
            const float* wrp = wr + (size_t)(256 * B_ + b) * C_;
            const float* wip = wi + (size_t)(256 * B_ + b) * C_;
            float br = 0.f, bi2 = 0.f;
#pragma unroll
            for (int c = 0; c < C_; ++c) {
                float xrv = xrn[((size_t)c * F_ + 256) * T_ + t];
                float xiv = xin[((size_t)c * F_ + 256) * T_ + t];
                br  += xrv * wrp[c] - xiv * wip[c];
                bi2 += xiv * wrp[c] + xrv * wip[c];
            }
            v = sqrtf(br * br + bi2 * bi2 + 1e-5f);
        }
        magS[0][trow][b] = v;
    }
    __syncthreads();
    {
        float2 mv = *(const float2*)&magS[0][t_loc][bq * 2];
        const float* wtail = wT + (size_t)256 * WKS + kg * 20;
#pragma unroll
        for (int j = 0; j < 20; ++j) {
            float wv = wtail[j];
            acc[0][j] += mv.x * wv;
            acc[1][j] += mv.y * wv;
        }
    }

    // ---- epilogue: relu+log, store (float4), per-b BN partial sums ----
    float s1f[2], s2f[2];
    s1f[0] = s1f[1] = s2f[0] = s2f[1] = 0.f;
    const int t = t0 + t_loc;
    if (t < T_) {
        float* obase = out + ((size_t)n * T_ + t) * BK_ + (bq * 2) * K_ + kg * 20;
#pragma unroll
        for (int i = 0; i < 2; ++i) {
            float vv[20];
#pragma unroll
            for (int j = 0; j < 20; ++j) {
                float v = fmaxf(acc[i][j], 0.0f);
                v = __logf(v + 1e-5f);
                vv[j] = v;
                s1f[i] += v;
                s2f[i] += v * v;
            }
            float* orow = obase + i * K_;
#pragma unroll
            for (int q = 0; q < 5; ++q)
                *(float4*)(orow + q * 4) =
                    make_float4(vv[q * 4], vv[q * 4 + 1], vv[q * 4 + 2], vv[q * 4 + 3]);
        }
    }
    const int wav = tid >> 6;
#pragma unroll
    for (int i = 0; i < 2; ++i) {
        double d1 = (double)s1f[i], d2 = (double)s2f[i];
#pragma unroll
        for (int off = 1; off < 16; off <<= 1) {   // reduce over 16 t-lanes
            d1 += __shfl_xor(d1, off);
            d2 += __shfl_xor(d2, off);
        }
        if (t_loc == 0) { redS1[wav][bq][i] = d1; redS2[wav][bq][i] = d2; }
    }
    __syncthreads();
    if (tid < 8) {   // b = 2*(tid>>1) + (tid&1)
        int bqi = tid >> 1, ii = tid & 1;
        partials[(size_t)bid * 16 + tid] =
            redS1[0][bqi][ii] + redS1[1][bqi][ii] + redS1[2][bqi][ii] + redS1[3][bqi][ii];
    } else if (tid >= 64 && tid < 72) {
        int id = tid - 64;
        int bqi = id >> 1, ii = id & 1;
        partials[(size_t)bid * 16 + 8 + id] =
            redS2[0][bqi][ii] + redS2[1][bqi][ii] + redS2[2][bqi][ii] + redS2[3][bqi][ii];
    }
}

// ---------------- reduce partials -> per-channel scale/shift ----------------
__global__ __launch_bounds__(256) void k_bnstats(
    const double* __restrict__ partials,
    const float* __restrict__ gamma, const float* __restrict__ beta,
    float* __restrict__ ss) {
    const int b = threadIdx.x >> 5;
    const int i = threadIdx.x & 31;
    double s1 = 0.0, s2 = 0.0;
    for (int j = i; j < NBLK; j += 32) {
        s1 += partials[(size_t)j * 16 + b];
        s2 += partials[(size_t)j * 16 + 8 + b];
    }
#pragma unroll
    for (int off = 16; off; off >>= 1) {
        s1 += __shfl_down(s1, off);
        s2 += __shfl_down(s2, off);
    }
    if (i == 0) {
        const double cnt = (double)N_ * T_ * K_;
        double mean = s1 / cnt;
        double var = s2 / cnt - mean * mean;
        float scale = gamma[b] * (float)(1.0 / sqrt(var + 1e-5));
        float shift = beta[b] - (float)mean * scale;
        ss[b] = scale;
        ss[B_ + b] = shift;
    }
}

// ---------------- apply BN in place over d_out ----------------
__global__ __launch_bounds__(256) void k_bnapply(float* __restrict__ out,
                                                 const float* __restrict__ ss) {
    size_t i4 = (size_t)blockIdx.x * 256 + threadIdx.x;
    int k4 = (int)(i4 % (BK_ / 4));
    int b = k4 / (K_ / 4);
    float scale = ss[b], shift = ss[B_ + b];
    float4* p = (float4*)out + i4;
    float4 v = *p;
    v.x = v.x * scale + shift;
    v.y = v.y * scale + shift;
    v.z = v.z * scale + shift;
    v.w = v.w * scale + shift;
    *p = v;
}

extern "C" void kernel_launch(void* const* d_in, const int* in_sizes, int n_in,
                              void* d_out, int out_size, void* d_ws, size_t ws_size,
                              hipStream_t stream) {
    const float* xr = (const float*)d_in[0];
    const float* xi = (const float*)d_in[1];
    const float* wr = (const float*)d_in[2];
    const float* wi = (const float*)d_in[3];
    const float* w_proj = (const float*)d_in[4];
    const float* gamma = (const float*)d_in[5];
    const float* beta = (const float*)d_in[6];
    float* out = (float*)d_out;

    float* wT = (float*)((char*)d_ws + WT_OFF);
    double* partials = (double*)((char*)d_ws + PART_OFF);
    float* ss = (float*)((char*)d_ws + SS_OFF);

    k_wt<<<F_, 80, 0, stream>>>(w_proj, wT);
    k_fused<<<NBLK, 256, 0, stream>>>(xr, xi, wr, wi, wT, out, partials);
    k_bnstats<<<1, 256, 0, stream>>>(partials, gamma, beta, ss);
    k_bnapply<<<10000, 256, 0, stream>>>(out, ss);
}

// Round 11
// 146.454 us; speedup vs baseline: 1.2268x; 1.0913x over previous
//
#include <hip/hip_runtime.h>
#include <math.h>

#define N_ 16
#define C_ 4
#define F_ 257
#define T_ 1000
#define B_ 8
#define K_ 80
#define BK_ 640
#define TT_ 16
#define NT_ 63            // ceil(1000/16)
#define NBLK (N_ * NT_)   // 1008 blocks ~= 4 per CU
#define MSTR 262          // magS row stride (words)
#define WKS  80           // wT row stride: plain [f][k]

// d_ws byte offsets
#define WT_OFF   0                            // 257*80*4 = 82240 B
#define PART_OFF (128 * 1024)
#define SS_OFF   (PART_OFF + NBLK * 16 * 8)

// ---- transpose w_proj [k][f] -> wT[f][k] ----
__global__ __launch_bounds__(80) void k_wt(const float* __restrict__ wp,
                                           float* __restrict__ wT) {
    int f = blockIdx.x;
    int k = threadIdx.x;
    wT[f * WKS + k] = wp[k * F_ + f];
}

// Fused beamform+mag (double-buffered LDS, 1 barrier/chunk) + projection GEMM
// (w scalar/SGPR) + relu+log + BN partial sums.
// CONVOY-BREAKER: each block starts its chunk loop at phase bid%7 and wraps,
// so co-resident blocks sit in different phases (stage vs GEMM overlap).
// Block = (n, 16-t tile), all 8 b, all 80 k.
// GEMM roles: wave kg=tid>>6 owns 20 k's (wave-uniform -> s_load);
//   lane: t_loc=tid&15, bq=(tid>>4)&3 (2 b's) -> 2b x 20k x 1t = 40 acc.
// Staging roles: sfr=tid>>3 (f-row 0..31), st2=tid&7 (2 t's each), all 8 b.
__global__ __launch_bounds__(256, 2) void k_fused(
    const float* __restrict__ xr, const float* __restrict__ xi,
    const float* __restrict__ wr, const float* __restrict__ wi,
    const float* __restrict__ wT,
    float* __restrict__ out, double* __restrict__ partials) {

    const int tid = threadIdx.x;
    const int bid = blockIdx.x;
    const int tt = bid % NT_;
    const int n  = bid / NT_;
    const int t0 = tt * TT_;

    __shared__ float magS[2][TT_][MSTR];   // double-buffered, 33.5 KB
    __shared__ double redS1[4][4][2];
    __shared__ double redS2[4][4][2];

    const int t_loc = tid & 15;
    const int bq    = (tid >> 4) & 3;                            // 2 b's: bq*2
    const int kg    = __builtin_amdgcn_readfirstlane(tid >> 6);  // 20 k's

    const int sfr = tid >> 3;           // staging f-row 0..31
    const int st2 = tid & 7;            // staging t-pair
    const int tb  = t0 + st2 * 2;
    const bool tload = (tb + 2 <= T_);

    const int s_ph = bid % 7;           // start phase 0..6 (convoy breaker)

    float acc[2][20];
#pragma unroll
    for (int i = 0; i < 2; ++i)
#pragma unroll
        for (int j = 0; j < 20; ++j) acc[i][j] = 0.f;

    const float* xrn = xr + (size_t)n * C_ * F_ * T_;
    const float* xin = xi + (size_t)n * C_ * F_ * T_;

    // -------- prefetch x for the first (rotated) chunk --------
    float2 pxr[C_], pxi[C_];
    if (tload) {
        const float* xrp = xrn + (size_t)(s_ph * 32 + sfr) * T_ + tb;
        const float* xip = xin + (size_t)(s_ph * 32 + sfr) * T_ + tb;
#pragma unroll
        for (int c = 0; c < C_; ++c) {
            pxr[c] = *(const float2*)(xrp + (size_t)c * F_ * T_);
            pxi[c] = *(const float2*)(xip + (size_t)c * F_ * T_);
        }
    }

    for (int it = 0; it < 8; ++it) {
        int ch = s_ph + it; if (ch >= 8) ch -= 8;   // rotated chunk index
        const int f0 = ch * 32;
        const int f  = f0 + sfr;
        const int pb = it & 1;          // buffer written this iteration

        // ---- beamform mag into LDS buf pb: thread = (sfr, st2) ----
        {
            float m[2][B_];
            if (tload) {
                float xrv[C_][2], xiv[C_][2];
#pragma unroll
                for (int c = 0; c < C_; ++c) {
                    xrv[c][0] = pxr[c].x; xrv[c][1] = pxr[c].y;
                    xiv[c][0] = pxi[c].x; xiv[c][1] = pxi[c].y;
                }
                const float* wrp = wr + (size_t)f * B_ * C_;
                const float* wip = wi + (size_t)f * B_ * C_;
#pragma unroll
                for (int b = 0; b < B_; ++b) {
                    float4 wrv = *(const float4*)(wrp + b * C_);
                    float4 wiv = *(const float4*)(wip + b * C_);
                    float wrc[4] = {wrv.x, wrv.y, wrv.z, wrv.w};
                    float wic[4] = {wiv.x, wiv.y, wiv.z, wiv.w};
#pragma unroll
                    for (int i = 0; i < 2; ++i) {
                        float br = 0.f, bi2 = 0.f;
#pragma unroll
                        for (int c = 0; c < C_; ++c) {
                            br  += xrv[c][i] * wrc[c] - xiv[c][i] * wic[c];
                            bi2 += xiv[c][i] * wrc[c] + xrv[c][i] * wic[c];
                        }
                        m[i][b] = sqrtf(br * br + bi2 * bi2 + 1e-5f);
                    }
                }
            } else {
#pragma unroll
                for (int i = 0; i < 2; ++i)
#pragma unroll
                    for (int b = 0; b < B_; ++b) m[i][b] = 0.f;
            }
#pragma unroll
            for (int i = 0; i < 2; ++i) {
                *(float4*)&magS[pb][st2 * 2 + i][sfr * 8] =
                    make_float4(m[i][0], m[i][1], m[i][2], m[i][3]);
                *(float4*)&magS[pb][st2 * 2 + i][sfr * 8 + 4] =
                    make_float4(m[i][4], m[i][5], m[i][6], m[i][7]);
            }
        }

        // ---- issue x prefetch for the next rotated chunk ----
        if (it < 7 && tload) {
            int ch2 = s_ph + it + 1; if (ch2 >= 8) ch2 -= 8;
            const float* xrp = xrn + (size_t)(ch2 * 32 + sfr) * T_ + tb;
            const float* xip = xin + (size_t)(ch2 * 32 + sfr) * T_ + tb;
#pragma unroll
            for (int c = 0; c < C_; ++c) {
                pxr[c] = *(const float2*)(xrp + (size_t)c * F_ * T_);
                pxi[c] = *(const float2*)(xip + (size_t)c * F_ * T_);
            }
        }

        __syncthreads();   // buf pb staged; prev GEMM (buf pb^1) already done

        // ---- GEMM over 32 f rows: mag 1xb64 LDS, w scalar (SGPR) ----
        const float* wchunk = wT + (size_t)f0 * WKS + kg * 20;  // wave-uniform
#pragma unroll 8
        for (int fc = 0; fc < 32; ++fc) {
            float2 mv = *(const float2*)&magS[pb][t_loc][fc * 8 + bq * 2];
            float wv[20];
#pragma unroll
            for (int j = 0; j < 20; ++j) wv[j] = wchunk[fc * WKS + j];
#pragma unroll
            for (int j = 0; j < 20; ++j) {
                acc[0][j] += mv.x * wv[j];
                acc[1][j] += mv.y * wv[j];
            }
        }
    }

    // ---- tail f = 256 (writes buf 0; last GEMM read buf 1) ----
    if (tid < 128) {
        int trow = tid >> 3;
        int b = tid & 7;
        int t = t0 + trow;
        float v = 0.f;
        if (t < T_) {
            const float* wrp = wr + (size_t)(256 * B_ + b) * C_;
            const float* wip = wi + (size_t)(256 * B_ + b) * C_;
            float br = 0.f, bi2 = 0.f;
#pragma unroll
            for (int c = 0; c < C_; ++c) {
                float xrv = xrn[((size_t)c * F_ + 256) * T_ + t];
                float xiv = xin[((size_t)c * F_ + 256) * T_ + t];
                br  += xrv * wrp[c] - xiv * wip[c];
                bi2 += xiv * wrp[c] + xrv * wip[c];
            }
            v = sqrtf(br * br + bi2 * bi2 + 1e-5f);
        }
        magS[0][trow][b] = v;
    }
    __syncthreads();
    {
        float2 mv = *(const float2*)&magS[0][t_loc][bq * 2];
        const float* wtail = wT + (size_t)256 * WKS + kg * 20;
#pragma unroll
        for (int j = 0; j < 20; ++j) {
            float wv = wtail[j];
            acc[0][j] += mv.x * wv;
            acc[1][j] += mv.y * wv;
        }
    }

    // ---- epilogue: relu+log, store (float4), per-b BN partial sums ----
    float s1f[2], s2f[2];
    s1f[0] = s1f[1] = s2f[0] = s2f[1] = 0.f;
    const int t = t0 + t_loc;
    if (t < T_) {
        float* obase = out + ((size_t)n * T_ + t) * BK_ + (bq * 2) * K_ + kg * 20;
#pragma unroll
        for (int i = 0; i < 2; ++i) {
            float vv[20];
#pragma unroll
            for (int j = 0; j < 20; ++j) {
                float v = fmaxf(acc[i][j], 0.0f);
                v = __logf(v + 1e-5f);
                vv[j] = v;
                s1f[i] += v;
                s2f[i] += v * v;
            }
            float* orow = obase + i * K_;
#pragma unroll
            for (int q = 0; q < 5; ++q)
                *(float4*)(orow + q * 4) =
                    make_float4(vv[q * 4], vv[q * 4 + 1], vv[q * 4 + 2], vv[q * 4 + 3]);
        }
    }
    const int wav = tid >> 6;
#pragma unroll
    for (int i = 0; i < 2; ++i) {
        double d1 = (double)s1f[i], d2 = (double)s2f[i];
#pragma unroll
        for (int off = 1; off < 16; off <<= 1) {   // reduce over 16 t-lanes
            d1 += __shfl_xor(d1, off);
            d2 += __shfl_xor(d2, off);
        }
        if (t_loc == 0) { redS1[wav][bq][i] = d1; redS2[wav][bq][i] = d2; }
    }
    __syncthreads();
    if (tid < 8) {   // b = 2*(tid>>1) + (tid&1)
        int bqi = tid >> 1, ii = tid & 1;
        partials[(size_t)bid * 16 + tid] =
            redS1[0][bqi][ii] + redS1[1][bqi][ii] + redS1[2][bqi][ii] + redS1[3][bqi][ii];
    } else if (tid >= 64 && tid < 72) {
        int id = tid - 64;
        int bqi = id >> 1, ii = id & 1;
        partials[(size_t)bid * 16 + 8 + id] =
            redS2[0][bqi][ii] + redS2[1][bqi][ii] + redS2[2][bqi][ii] + redS2[3][bqi][ii];
    }
}

// ---------------- reduce partials -> per-channel scale/shift ----------------
__global__ __launch_bounds__(256) void k_bnstats(
    const double* __restrict__ partials,
    const float* __restrict__ gamma, const float* __restrict__ beta,
    float* __restrict__ ss) {
    const int b = threadIdx.x >> 5;
    const int i = threadIdx.x & 31;
    double s1 = 0.0, s2 = 0.0;
    for (int j = i; j < NBLK; j += 32) {
        s1 += partials[(size_t)j * 16 + b];
        s2 += partials[(size_t)j * 16 + 8 + b];
    }
#pragma unroll
    for (int off = 16; off; off >>= 1) {
        s1 += __shfl_down(s1, off);
        s2 += __shfl_down(s2, off);
    }
    if (i == 0) {
        const double cnt = (double)N_ * T_ * K_;
        double mean = s1 / cnt;
        double var = s2 / cnt - mean * mean;
        float scale = gamma[b] * (float)(1.0 / sqrt(var + 1e-5));
        float shift = beta[b] - (float)mean * scale;
        ss[b] = scale;
        ss[B_ + b] = shift;
    }
}

// ---------------- apply BN in place over d_out ----------------
__global__ __launch_bounds__(256) void k_bnapply(float* __restrict__ out,
                                                 const float* __restrict__ ss) {
    size_t i4 = (size_t)blockIdx.x * 256 + threadIdx.x;
    int k4 = (int)(i4 % (BK_ / 4));
    int b = k4 / (K_ / 4);
    float scale = ss[b], shift = ss[B_ + b];
    float4* p = (float4*)out + i4;
    float4 v = *p;
    v.x = v.x * scale + shift;
    v.y = v.y * scale + shift;
    v.z = v.z * scale + shift;
    v.w = v.w * scale + shift;
    *p = v;
}

extern "C" void kernel_launch(void* const* d_in, const int* in_sizes, int n_in,
                              void* d_out, int out_size, void* d_ws, size_t ws_size,
                              hipStream_t stream) {
    const float* xr = (const float*)d_in[0];
    const float* xi = (const float*)d_in[1];
    const float* wr = (const float*)d_in[2];
    const float* wi = (const float*)d_in[3];
    const float* w_proj = (const float*)d_in[4];
    const float* gamma = (const float*)d_in[5];
    const float* beta = (const float*)d_in[6];
    float* out = (float*)d_out;

    float* wT = (float*)((char*)d_ws + WT_OFF);
    double* partials = (double*)((char*)d_ws + PART_OFF);
    float* ss = (float*)((char*)d_ws + SS_OFF);

    k_wt<<<F_, 80, 0, stream>>>(w_proj, wT);
    k_fused<<<NBLK, 256, 0, stream>>>(xr, xi, wr, wi, wT, out, partials);
    k_bnstats<<<1, 256, 0, stream>>>(partials, gamma, beta, ss);
    k_bnapply<<<10000, 256, 0, stream>>>(out, ss);
}